// Round 11
// baseline (630.236 us; speedup 1.0000x reference)
//
#include <hip/hip_runtime.h>

#define VOCAB 32000
#define EMB 32
#define HID 16
#define SEQ 128
#define BATCH 32
#define NROW (SEQ * BATCH)  // 4096 rows = (t, b) pairs
#define REP 3     // ATTRIBUTION ROUND: repeat vocab-kernel work 3x so each
                  // dispatch exceeds the ~305us harness fills and surfaces
                  // in the top-5 counter rows. Idempotent + deterministic.

typedef float f32x2 __attribute__((ext_vector_type(2)));
typedef float f32x4 __attribute__((ext_vector_type(4)));

// ---------------------------------------------------------------------------
// K1: embedding gather + 128-step tanh recurrence (unchanged, rounds 1-9).
// ---------------------------------------------------------------------------
__global__ __launch_bounds__(512) void rnn_recur(
    const int* __restrict__ idx, const float* __restrict__ lookup,
    const float* __restrict__ Wx, const float* __restrict__ Wh,
    float* __restrict__ Hout)
{
    __shared__ float sWx[EMB][HID];
    __shared__ float sWh[HID][HID];
    __shared__ float sH[BATCH][HID];
    __shared__ float sX[BATCH][EMB + 1];
    __shared__ int   sIdx[SEQ * BATCH];  // 16 KB

    const int tid = threadIdx.x;
    const int b = tid >> 4, j = tid & 15;

    sWx[tid >> 4][tid & 15] = Wx[tid];
    if (tid < HID * HID) sWh[tid >> 4][tid & 15] = Wh[tid];
    sH[b][j] = 1.0f;  // torch inits H to ones
    #pragma unroll
    for (int i = tid; i < SEQ * BATCH; i += 512) sIdx[i] = idx[i];
    __syncthreads();

    const int el = 2 * j;  // thread (b,j) owns X[t][b][2j..2j+1]
    float2 x0 = *(const float2*)(lookup + sIdx[0 * BATCH + b] * EMB + el);
    float2 x1 = *(const float2*)(lookup + sIdx[1 * BATCH + b] * EMB + el);
    float2 x2 = *(const float2*)(lookup + sIdx[2 * BATCH + b] * EMB + el);
    float2 x3 = *(const float2*)(lookup + sIdx[3 * BATCH + b] * EMB + el);

#define RNN_STEP(XR, T)                                                     \
    {                                                                       \
        sX[b][el] = XR.x; sX[b][el + 1] = XR.y;                             \
        if ((T) + 4 < SEQ) {                                                \
            int row = sIdx[((T) + 4) * BATCH + b];                          \
            XR = *(const float2*)(lookup + row * EMB + el);                 \
        }                                                                   \
        float a0 = 0.f, a1 = 0.f, a2 = 0.f, a3 = 0.f;                       \
        _Pragma("unroll")                                                   \
        for (int e = 0; e < EMB; e += 4) {                                  \
            a0 += sX[b][e + 0] * sWx[e + 0][j];                             \
            a1 += sX[b][e + 1] * sWx[e + 1][j];                             \
            a2 += sX[b][e + 2] * sWx[e + 2][j];                             \
            a3 += sX[b][e + 3] * sWx[e + 3][j];                             \
        }                                                                   \
        _Pragma("unroll")                                                   \
        for (int k = 0; k < HID; k += 4) {                                  \
            a0 += sH[b][k + 0] * sWh[k + 0][j];                             \
            a1 += sH[b][k + 1] * sWh[k + 1][j];                             \
            a2 += sH[b][k + 2] * sWh[k + 2][j];                             \
            a3 += sH[b][k + 3] * sWh[k + 3][j];                             \
        }                                                                   \
        float a = (a0 + a1) + (a2 + a3);                                    \
        float e2 = __expf(2.f * a);      /* tanh = 1 - 2/(e^{2a}+1) */      \
        float h = 1.f - 2.f / (e2 + 1.f);                                   \
        sH[b][j] = h;                                                       \
        Hout[(T) * (BATCH * HID) + tid] = h;                                \
    }

    for (int t = 0; t < SEQ; t += 4) {
        RNN_STEP(x0, t + 0)
        RNN_STEP(x1, t + 1)
        RNN_STEP(x2, t + 2)
        RNN_STEP(x3, t + 3)
    }
#undef RNN_STEP
}

// ---------------------------------------------------------------------------
// Vocab passes (round-9 structure: RV=64, grid 1024, 4 blocks/CU, reg-Wo,
// NT stores) wrapped in a REP loop with a memory-clobber between reps so
// the compiler re-loads and re-computes each repetition.
// ---------------------------------------------------------------------------
#define RV 64     // rows per block
#define VSK 2048  // vocab cols per block slice

__global__ __launch_bounds__(512, 4) void sum_exp_x3(
    const float* __restrict__ H, const float* __restrict__ Wo,
    float* __restrict__ P)
{
    __shared__ __align__(16) float sH[RV * HID];  // 4 KB
    __shared__ float part[8][RV];                 // 2 KB

    const int tid = threadIdx.x;
    const int wave = tid >> 6;
    const int vtile = blockIdx.x & 15;
    const int row0 = (blockIdx.x >> 4) * RV;

    if (tid < RV * HID / 4)
        *(float4*)(sH + 4 * tid) = *(const float4*)(H + row0 * HID + 4 * tid);
    __syncthreads();

    const int v = vtile * VSK + 4 * tid;
    const bool active = (v < VOCAB);
    const int vc = active ? v : (VOCAB - 4);
    const float amask = active ? 1.f : 0.f;
    const f32x4* sH4 = (const f32x4*)sH;

    #pragma unroll 1
    for (int rep = 0; rep < REP; ++rep) {
        f32x2 wlo[HID], whi[HID];
        #pragma unroll
        for (int k = 0; k < HID; ++k) {
            f32x4 w4 = *(const f32x4*)(Wo + (size_t)k * VOCAB + vc);
            wlo[k] = w4.xy; whi[k] = w4.zw;
        }
        for (int r = 0; r < RV; ++r) {
            f32x2 l01 = {0.f, 0.f}, l23 = {0.f, 0.f};
            #pragma unroll
            for (int q = 0; q < 4; ++q) {
                f32x4 hv = sH4[r * 4 + q];  // uniform addr b128 broadcast
                l01 += hv.x * wlo[4*q+0]; l23 += hv.x * whi[4*q+0];
                l01 += hv.y * wlo[4*q+1]; l23 += hv.y * whi[4*q+1];
                l01 += hv.z * wlo[4*q+2]; l23 += hv.z * whi[4*q+2];
                l01 += hv.w * wlo[4*q+3]; l23 += hv.w * whi[4*q+3];
            }
            float s = amask * ((__expf(l01.x) + __expf(l01.y)) +
                               (__expf(l23.x) + __expf(l23.y)));
            #pragma unroll
            for (int off = 32; off > 0; off >>= 1)
                s += __shfl_xor(s, off);
            if ((tid & 63) == 0) part[wave][r] = s;
        }
        __syncthreads();
        if (tid < RV) {
            float tot = 0.f;
            #pragma unroll
            for (int w = 0; w < 8; ++w) tot += part[w][tid];
            P[(size_t)vtile * NROW + row0 + tid] = tot;  // idempotent
        }
        asm volatile("" ::: "memory");  // force real re-execution per rep
        __syncthreads();
    }
}

__global__ __launch_bounds__(512, 4) void write_x3(
    const float* __restrict__ H, const float* __restrict__ Wo,
    const float* __restrict__ P, float* __restrict__ out)
{
    __shared__ __align__(16) float sH[RV * HID];  // 4 KB
    __shared__ __align__(16) float sLogS[RV];

    const int tid = threadIdx.x;
    const int vtile = blockIdx.x & 15;
    const int row0 = (blockIdx.x >> 4) * RV;

    if (tid < RV * HID / 4)
        *(float4*)(sH + 4 * tid) = *(const float4*)(H + row0 * HID + 4 * tid);
    if (tid < RV) {
        float tot = 0.f;
        #pragma unroll
        for (int p = 0; p < 16; ++p) tot += P[(size_t)p * NROW + row0 + tid];
        sLogS[tid] = __logf(tot);
    }
    __syncthreads();

    const int v = vtile * VSK + 4 * tid;
    if (v >= VOCAB) return;  // tail; no barriers below

    const f32x4* sH4 = (const f32x4*)sH;
    const f32x4* sLS4 = (const f32x4*)sLogS;

    #pragma unroll 1
    for (int rep = 0; rep < REP; ++rep) {
        f32x2 wlo[HID], whi[HID];
        #pragma unroll
        for (int k = 0; k < HID; ++k) {
            f32x4 w4 = *(const f32x4*)(Wo + (size_t)k * VOCAB + v);
            wlo[k] = w4.xy; whi[k] = w4.zw;
        }
        float* orow = out + (size_t)row0 * VOCAB + v;
        for (int r4 = 0; r4 < RV; r4 += 4) {
            f32x4 ls4 = sLS4[r4 >> 2];
            #pragma unroll
            for (int rr = 0; rr < 4; ++rr) {
                const int r = r4 + rr;
                f32x2 l01 = {0.f, 0.f}, l23 = {0.f, 0.f};
                #pragma unroll
                for (int q = 0; q < 4; ++q) {
                    f32x4 hv = sH4[r * 4 + q];
                    l01 += hv.x * wlo[4*q+0]; l23 += hv.x * whi[4*q+0];
                    l01 += hv.y * wlo[4*q+1]; l23 += hv.y * whi[4*q+1];
                    l01 += hv.z * wlo[4*q+2]; l23 += hv.z * whi[4*q+2];
                    l01 += hv.w * wlo[4*q+3]; l23 += hv.w * whi[4*q+3];
                }
                const float ls = (rr == 0) ? ls4.x : (rr == 1) ? ls4.y
                               : (rr == 2) ? ls4.z : ls4.w;
                f32x4 o;
                o.xy = l01 - ls;
                o.zw = l23 - ls;
                __builtin_nontemporal_store(o, (f32x4*)orow);  // idempotent
                orow += VOCAB;
            }
        }
        asm volatile("" ::: "memory");  // force real re-execution per rep
    }
}

extern "C" void kernel_launch(void* const* d_in, const int* in_sizes, int n_in,
                              void* d_out, int out_size, void* d_ws, size_t ws_size,
                              hipStream_t stream) {
    const int*   idx    = (const int*)d_in[0];    // [SEQ, BATCH] int32
    const float* lookup = (const float*)d_in[1];  // [VOCAB, EMB]
    const float* Wx     = (const float*)d_in[2];  // [EMB, HID]
    const float* Wh     = (const float*)d_in[3];  // [HID, HID]
    const float* Wo     = (const float*)d_in[4];  // [HID, VOCAB]
    float* out = (float*)d_out;                   // [SEQ, BATCH, VOCAB]

    // ws layout: H (256 KB) | P partials 16x4096 (256 KB)
    float* Hbuf = (float*)d_ws;
    float* P    = Hbuf + NROW * HID;

    rnn_recur<<<1, 512, 0, stream>>>(idx, lookup, Wx, Wh, Hbuf);
    sum_exp_x3<<<16 * (NROW / RV), 512, 0, stream>>>(Hbuf, Wo, P);
    write_x3<<<16 * (NROW / RV), 512, 0, stream>>>(Hbuf, Wo, P, out);
}

// Round 12
// 487.504 us; speedup vs baseline: 1.2928x; 1.2928x over previous
//
#include <hip/hip_runtime.h>

#define VOCAB 32000
#define EMB 32
#define HID 16
#define SEQ 128
#define BATCH 32
#define NROW (SEQ * BATCH)  // 4096 rows = (t, b) pairs
#define REPS 4    // sum_exp only: surfaces it above the ~305us harness fills
                  // if the DPP fix does NOT work (embedded attribution)

typedef float f32x2 __attribute__((ext_vector_type(2)));
typedef float f32x4 __attribute__((ext_vector_type(4)));

// Wave64 sum via DPP (VALU pipe, no ds_bpermute): row_shr 1/2/4/8 builds
// 16-lane prefix tails, row_bcast:15/31 folds rows. Full sum lands in
// lane 63. old=0 + bound_ctrl=0 -> invalid lanes contribute 0.
__device__ __forceinline__ float wave64_sum_dpp(float x) {
    int t;
#define DPP_ADD(ctrl, rmask)                                                \
    t = __builtin_amdgcn_update_dpp(0, __float_as_int(x), ctrl, rmask, 0xf, \
                                    false);                                 \
    x += __int_as_float(t);
    DPP_ADD(0x111, 0xf)  // row_shr:1
    DPP_ADD(0x112, 0xf)  // row_shr:2
    DPP_ADD(0x114, 0xf)  // row_shr:4
    DPP_ADD(0x118, 0xf)  // row_shr:8
    DPP_ADD(0x142, 0xa)  // row_bcast:15 -> rows 1,3
    DPP_ADD(0x143, 0xc)  // row_bcast:31 -> rows 2,3
#undef DPP_ADD
    return x;  // lane 63 holds the wave total
}

// ---------------------------------------------------------------------------
// K1: embedding gather + 128-step tanh recurrence (unchanged, rounds 1-9).
// ---------------------------------------------------------------------------
__global__ __launch_bounds__(512) void rnn_recur(
    const int* __restrict__ idx, const float* __restrict__ lookup,
    const float* __restrict__ Wx, const float* __restrict__ Wh,
    float* __restrict__ Hout)
{
    __shared__ float sWx[EMB][HID];
    __shared__ float sWh[HID][HID];
    __shared__ float sH[BATCH][HID];
    __shared__ float sX[BATCH][EMB + 1];
    __shared__ int   sIdx[SEQ * BATCH];  // 16 KB

    const int tid = threadIdx.x;
    const int b = tid >> 4, j = tid & 15;

    sWx[tid >> 4][tid & 15] = Wx[tid];
    if (tid < HID * HID) sWh[tid >> 4][tid & 15] = Wh[tid];
    sH[b][j] = 1.0f;  // torch inits H to ones
    #pragma unroll
    for (int i = tid; i < SEQ * BATCH; i += 512) sIdx[i] = idx[i];
    __syncthreads();

    const int el = 2 * j;  // thread (b,j) owns X[t][b][2j..2j+1]
    float2 x0 = *(const float2*)(lookup + sIdx[0 * BATCH + b] * EMB + el);
    float2 x1 = *(const float2*)(lookup + sIdx[1 * BATCH + b] * EMB + el);
    float2 x2 = *(const float2*)(lookup + sIdx[2 * BATCH + b] * EMB + el);
    float2 x3 = *(const float2*)(lookup + sIdx[3 * BATCH + b] * EMB + el);

#define RNN_STEP(XR, T)                                                     \
    {                                                                       \
        sX[b][el] = XR.x; sX[b][el + 1] = XR.y;                             \
        if ((T) + 4 < SEQ) {                                                \
            int row = sIdx[((T) + 4) * BATCH + b];                          \
            XR = *(const float2*)(lookup + row * EMB + el);                 \
        }                                                                   \
        float a0 = 0.f, a1 = 0.f, a2 = 0.f, a3 = 0.f;                       \
        _Pragma("unroll")                                                   \
        for (int e = 0; e < EMB; e += 4) {                                  \
            a0 += sX[b][e + 0] * sWx[e + 0][j];                             \
            a1 += sX[b][e + 1] * sWx[e + 1][j];                             \
            a2 += sX[b][e + 2] * sWx[e + 2][j];                             \
            a3 += sX[b][e + 3] * sWx[e + 3][j];                             \
        }                                                                   \
        _Pragma("unroll")                                                   \
        for (int k = 0; k < HID; k += 4) {                                  \
            a0 += sH[b][k + 0] * sWh[k + 0][j];                             \
            a1 += sH[b][k + 1] * sWh[k + 1][j];                             \
            a2 += sH[b][k + 2] * sWh[k + 2][j];                             \
            a3 += sH[b][k + 3] * sWh[k + 3][j];                             \
        }                                                                   \
        float a = (a0 + a1) + (a2 + a3);                                    \
        float e2 = __expf(2.f * a);      /* tanh = 1 - 2/(e^{2a}+1) */      \
        float h = 1.f - 2.f / (e2 + 1.f);                                   \
        sH[b][j] = h;                                                       \
        Hout[(T) * (BATCH * HID) + tid] = h;                                \
    }

    for (int t = 0; t < SEQ; t += 4) {
        RNN_STEP(x0, t + 0)
        RNN_STEP(x1, t + 1)
        RNN_STEP(x2, t + 2)
        RNN_STEP(x3, t + 3)
    }
#undef RNN_STEP
}

// ---------------------------------------------------------------------------
// Vocab passes (R9 structure: RV=64, grid 1024 = 4 blocks/CU, reg-Wo, NT
// stores). sum_exp reduction switched from 6x ds_bpermute butterfly to
// 6x DPP VALU adds (theory: 384 bpermute/thread serialized the per-CU DS
// pipe ~30us + 6-deep 30cyc latency chains = the ~135us vs ~40us gap).
// ---------------------------------------------------------------------------
#define RV 64     // rows per block
#define VSK 2048  // vocab cols per block slice

__global__ __launch_bounds__(512, 4) void sum_exp_x4(
    const float* __restrict__ H, const float* __restrict__ Wo,
    float* __restrict__ P)
{
    __shared__ __align__(16) float sH[RV * HID];  // 4 KB
    __shared__ float part[8][RV];                 // 2 KB

    const int tid = threadIdx.x;
    const int wave = tid >> 6;
    const int vtile = blockIdx.x & 15;
    const int row0 = (blockIdx.x >> 4) * RV;

    if (tid < RV * HID / 4)
        *(float4*)(sH + 4 * tid) = *(const float4*)(H + row0 * HID + 4 * tid);
    __syncthreads();

    const int v = vtile * VSK + 4 * tid;
    const bool active = (v < VOCAB);
    const int vc = active ? v : (VOCAB - 4);
    const float amask = active ? 1.f : 0.f;
    const f32x4* sH4 = (const f32x4*)sH;

    #pragma unroll 1
    for (int rep = 0; rep < REPS; ++rep) {
        f32x2 wlo[HID], whi[HID];
        #pragma unroll
        for (int k = 0; k < HID; ++k) {
            f32x4 w4 = *(const f32x4*)(Wo + (size_t)k * VOCAB + vc);
            wlo[k] = w4.xy; whi[k] = w4.zw;
        }
        for (int r = 0; r < RV; ++r) {
            f32x2 l01 = {0.f, 0.f}, l23 = {0.f, 0.f};
            #pragma unroll
            for (int q = 0; q < 4; ++q) {
                f32x4 hv = sH4[r * 4 + q];  // uniform addr b128 broadcast
                l01 += hv.x * wlo[4*q+0]; l23 += hv.x * whi[4*q+0];
                l01 += hv.y * wlo[4*q+1]; l23 += hv.y * whi[4*q+1];
                l01 += hv.z * wlo[4*q+2]; l23 += hv.z * whi[4*q+2];
                l01 += hv.w * wlo[4*q+3]; l23 += hv.w * whi[4*q+3];
            }
            float s = amask * ((__expf(l01.x) + __expf(l01.y)) +
                               (__expf(l23.x) + __expf(l23.y)));
            s = wave64_sum_dpp(s);            // VALU-pipe reduce, no DS ops
            if ((tid & 63) == 63) part[wave][r] = s;  // lane 63 has total
        }
        __syncthreads();
        if (tid < RV) {
            float tot = 0.f;
            #pragma unroll
            for (int w = 0; w < 8; ++w) tot += part[w][tid];
            P[(size_t)vtile * NROW + row0 + tid] = tot;  // idempotent
        }
        asm volatile("" ::: "memory");  // force real re-execution per rep
        __syncthreads();
    }
}

// K3: output pass (REP=1; characterized in R11: ~107us at the ~4.9 TB/s
// NT-store ceiling, WRITE 1.0x ideal, FETCH ~3 MB). logS fused; NT stores.
__global__ __launch_bounds__(512, 4) void write_logits(
    const float* __restrict__ H, const float* __restrict__ Wo,
    const float* __restrict__ P, float* __restrict__ out)
{
    __shared__ __align__(16) float sH[RV * HID];  // 4 KB
    __shared__ __align__(16) float sLogS[RV];

    const int tid = threadIdx.x;
    const int vtile = blockIdx.x & 15;
    const int row0 = (blockIdx.x >> 4) * RV;

    if (tid < RV * HID / 4)
        *(float4*)(sH + 4 * tid) = *(const float4*)(H + row0 * HID + 4 * tid);
    if (tid < RV) {
        float tot = 0.f;
        #pragma unroll
        for (int p = 0; p < 16; ++p) tot += P[(size_t)p * NROW + row0 + tid];
        sLogS[tid] = __logf(tot);
    }
    __syncthreads();

    const int v = vtile * VSK + 4 * tid;
    if (v >= VOCAB) return;  // tail; no barriers below

    f32x2 wlo[HID], whi[HID];
    #pragma unroll
    for (int k = 0; k < HID; ++k) {
        f32x4 w4 = *(const f32x4*)(Wo + (size_t)k * VOCAB + v);
        wlo[k] = w4.xy; whi[k] = w4.zw;
    }
    const f32x4* sH4 = (const f32x4*)sH;
    const f32x4* sLS4 = (const f32x4*)sLogS;

    float* orow = out + (size_t)row0 * VOCAB + v;
    for (int r4 = 0; r4 < RV; r4 += 4) {
        f32x4 ls4 = sLS4[r4 >> 2];
        #pragma unroll
        for (int rr = 0; rr < 4; ++rr) {
            const int r = r4 + rr;
            f32x2 l01 = {0.f, 0.f}, l23 = {0.f, 0.f};
            #pragma unroll
            for (int q = 0; q < 4; ++q) {
                f32x4 hv = sH4[r * 4 + q];
                l01 += hv.x * wlo[4*q+0]; l23 += hv.x * whi[4*q+0];
                l01 += hv.y * wlo[4*q+1]; l23 += hv.y * whi[4*q+1];
                l01 += hv.z * wlo[4*q+2]; l23 += hv.z * whi[4*q+2];
                l01 += hv.w * wlo[4*q+3]; l23 += hv.w * whi[4*q+3];
            }
            const float ls = (rr == 0) ? ls4.x : (rr == 1) ? ls4.y
                           : (rr == 2) ? ls4.z : ls4.w;
            f32x4 o;
            o.xy = l01 - ls;
            o.zw = l23 - ls;
            __builtin_nontemporal_store(o, (f32x4*)orow);
            orow += VOCAB;
        }
    }
}

extern "C" void kernel_launch(void* const* d_in, const int* in_sizes, int n_in,
                              void* d_out, int out_size, void* d_ws, size_t ws_size,
                              hipStream_t stream) {
    const int*   idx    = (const int*)d_in[0];    // [SEQ, BATCH] int32
    const float* lookup = (const float*)d_in[1];  // [VOCAB, EMB]
    const float* Wx     = (const float*)d_in[2];  // [EMB, HID]
    const float* Wh     = (const float*)d_in[3];  // [HID, HID]
    const float* Wo     = (const float*)d_in[4];  // [HID, VOCAB]
    float* out = (float*)d_out;                   // [SEQ, BATCH, VOCAB]

    // ws layout: H (256 KB) | P partials 16x4096 (256 KB)
    float* Hbuf = (float*)d_ws;
    float* P    = Hbuf + NROW * HID;

    rnn_recur<<<1, 512, 0, stream>>>(idx, lookup, Wx, Wh, Hbuf);
    sum_exp_x4<<<16 * (NROW / RV), 512, 0, stream>>>(Hbuf, Wo, P);
    write_logits<<<16 * (NROW / RV), 512, 0, stream>>>(Hbuf, Wo, P, out);
}

// Round 13
// 257.569 us; speedup vs baseline: 2.4469x; 1.8927x over previous
//
#include <hip/hip_runtime.h>

#define VOCAB 32000
#define EMB 32
#define HID 16
#define SEQ 128
#define BATCH 32
#define NROW (SEQ * BATCH)  // 4096 rows

typedef float f32x2 __attribute__((ext_vector_type(2)));
typedef float f32x4 __attribute__((ext_vector_type(4)));

// v_pk_fma_f32 with H broadcast from an SGPR pair via op_sel (CDNA packed-f32
// idiom): acc.lo += h*w.lo, acc.hi += h*w.hi, h = word0 (lo) or word1 (hi)
// of the 64-bit scalar operand. One s_load_dwordx2 feeds two k-steps.
__device__ __forceinline__ void pk_fma_lo(f32x2& acc, double h2, f32x2 w) {
    asm("v_pk_fma_f32 %0, %1, %2, %0 op_sel:[0,0,0] op_sel_hi:[0,1,1]"
        : "+v"(acc) : "s"(h2), "v"(w));
}
__device__ __forceinline__ void pk_fma_hi(f32x2& acc, double h2, f32x2 w) {
    asm("v_pk_fma_f32 %0, %1, %2, %0 op_sel:[1,0,0] op_sel_hi:[1,1,1]"
        : "+v"(acc) : "s"(h2), "v"(w));
}

// Wave64 sum via DPP (VALU pipe, no DS ops); total lands in lane 63.
__device__ __forceinline__ float wave64_sum_dpp(float x) {
    int t;
#define DPP_ADD(ctrl, rmask)                                                \
    t = __builtin_amdgcn_update_dpp(0, __float_as_int(x), ctrl, rmask, 0xf, \
                                    false);                                 \
    x += __int_as_float(t);
    DPP_ADD(0x111, 0xf)  // row_shr:1
    DPP_ADD(0x112, 0xf)  // row_shr:2
    DPP_ADD(0x114, 0xf)  // row_shr:4
    DPP_ADD(0x118, 0xf)  // row_shr:8
    DPP_ADD(0x142, 0xa)  // row_bcast:15
    DPP_ADD(0x143, 0xc)  // row_bcast:31
#undef DPP_ADD
    return x;
}

// ---------------------------------------------------------------------------
// K1: embedding gather + 128-step tanh recurrence (unchanged, rounds 1-12).
// ---------------------------------------------------------------------------
__global__ __launch_bounds__(512) void rnn_recur(
    const int* __restrict__ idx, const float* __restrict__ lookup,
    const float* __restrict__ Wx, const float* __restrict__ Wh,
    float* __restrict__ Hout)
{
    __shared__ float sWx[EMB][HID];
    __shared__ float sWh[HID][HID];
    __shared__ float sH[BATCH][HID];
    __shared__ float sX[BATCH][EMB + 1];
    __shared__ int   sIdx[SEQ * BATCH];

    const int tid = threadIdx.x;
    const int b = tid >> 4, j = tid & 15;

    sWx[tid >> 4][tid & 15] = Wx[tid];
    if (tid < HID * HID) sWh[tid >> 4][tid & 15] = Wh[tid];
    sH[b][j] = 1.0f;  // torch inits H to ones
    #pragma unroll
    for (int i = tid; i < SEQ * BATCH; i += 512) sIdx[i] = idx[i];
    __syncthreads();

    const int el = 2 * j;
    float2 x0 = *(const float2*)(lookup + sIdx[0 * BATCH + b] * EMB + el);
    float2 x1 = *(const float2*)(lookup + sIdx[1 * BATCH + b] * EMB + el);
    float2 x2 = *(const float2*)(lookup + sIdx[2 * BATCH + b] * EMB + el);
    float2 x3 = *(const float2*)(lookup + sIdx[3 * BATCH + b] * EMB + el);

#define RNN_STEP(XR, T)                                                     \
    {                                                                       \
        sX[b][el] = XR.x; sX[b][el + 1] = XR.y;                             \
        if ((T) + 4 < SEQ) {                                                \
            int row = sIdx[((T) + 4) * BATCH + b];                          \
            XR = *(const float2*)(lookup + row * EMB + el);                 \
        }                                                                   \
        float a0 = 0.f, a1 = 0.f, a2 = 0.f, a3 = 0.f;                       \
        _Pragma("unroll")                                                   \
        for (int e = 0; e < EMB; e += 4) {                                  \
            a0 += sX[b][e + 0] * sWx[e + 0][j];                             \
            a1 += sX[b][e + 1] * sWx[e + 1][j];                             \
            a2 += sX[b][e + 2] * sWx[e + 2][j];                             \
            a3 += sX[b][e + 3] * sWx[e + 3][j];                             \
        }                                                                   \
        _Pragma("unroll")                                                   \
        for (int k = 0; k < HID; k += 4) {                                  \
            a0 += sH[b][k + 0] * sWh[k + 0][j];                             \
            a1 += sH[b][k + 1] * sWh[k + 1][j];                             \
            a2 += sH[b][k + 2] * sWh[k + 2][j];                             \
            a3 += sH[b][k + 3] * sWh[k + 3][j];                             \
        }                                                                   \
        float a = (a0 + a1) + (a2 + a3);                                    \
        float e2 = __expf(2.f * a);      /* tanh = 1 - 2/(e^{2a}+1) */      \
        float h = 1.f - 2.f / (e2 + 1.f);                                   \
        sH[b][j] = h;                                                       \
        Hout[(T) * (BATCH * HID) + tid] = h;                                \
    }

    for (int t = 0; t < SEQ; t += 4) {
        RNN_STEP(x0, t + 0)
        RNN_STEP(x1, t + 1)
        RNN_STEP(x2, t + 2)
        RNN_STEP(x3, t + 3)
    }
#undef RNN_STEP
}

// ---------------------------------------------------------------------------
// Vocab passes. R12 diagnosis: sum_exp VALU-issue-bound (VALUBusy 85%).
// This round: H via uniform s_load (no LDS, no staging barrier) + real
// v_pk_fma_f32 (SGPR-broadcast H) halves FMA issue; sum pass pre-scales Wo
// by log2e so exp = raw v_exp_f32 (exp2). NT stores + cache-independent Wo
// (L1/regs) retained (rounds 1-6 lessons).
// ---------------------------------------------------------------------------
#define RV 64     // rows per block
#define VSK 2048  // vocab cols per block slice

__global__ __launch_bounds__(512, 4) void sum_exp_partial(
    const float* __restrict__ H, const float* __restrict__ Wo,
    float* __restrict__ P)
{
    __shared__ float part[8][RV];  // per-wave partials

    const int tid = threadIdx.x;
    const int wave = tid >> 6;
    const int vtile = blockIdx.x & 15;
    const int row0 = (blockIdx.x >> 4) * RV;

    const int v = vtile * VSK + 4 * tid;
    const bool active = (v < VOCAB);
    const int vc = active ? v : (VOCAB - 4);
    const float amask = active ? 1.f : 0.f;

    // Wo slice, pre-scaled by log2(e): exp(l) = exp2(l * log2e)
    const float LOG2E = 1.4426950408889634f;
    f32x2 wlo[HID], whi[HID];
    #pragma unroll
    for (int k = 0; k < HID; ++k) {
        f32x4 w4 = *(const f32x4*)(Wo + (size_t)k * VOCAB + vc);
        wlo[k].x = w4.x * LOG2E; wlo[k].y = w4.y * LOG2E;
        whi[k].x = w4.z * LOG2E; whi[k].y = w4.w * LOG2E;
    }

    // H rows as uniform 64-bit scalar loads (s_load_dwordx2 pairs)
    const double* H2 = (const double*)(H + row0 * HID);

    #pragma unroll 2
    for (int r = 0; r < RV; ++r) {
        f32x2 a01 = {0.f, 0.f}, a23 = {0.f, 0.f};
        f32x2 b01 = {0.f, 0.f}, b23 = {0.f, 0.f};  // parity-split chains
        #pragma unroll
        for (int q = 0; q < 8; ++q) {
            double h2 = H2[r * 8 + q];  // h_{2q}, h_{2q+1} (uniform)
            pk_fma_lo(a01, h2, wlo[2 * q]);
            pk_fma_lo(a23, h2, whi[2 * q]);
            pk_fma_hi(b01, h2, wlo[2 * q + 1]);
            pk_fma_hi(b23, h2, whi[2 * q + 1]);
        }
        f32x2 l01 = a01 + b01, l23 = a23 + b23;
        float s = amask *
            ((__builtin_amdgcn_exp2f(l01.x) + __builtin_amdgcn_exp2f(l01.y)) +
             (__builtin_amdgcn_exp2f(l23.x) + __builtin_amdgcn_exp2f(l23.y)));
        s = wave64_sum_dpp(s);                    // VALU-pipe reduce
        if ((tid & 63) == 63) part[wave][r] = s;  // lane 63 holds total
    }
    __syncthreads();
    if (tid < RV) {
        float tot = 0.f;
        #pragma unroll
        for (int w = 0; w < 8; ++w) tot += part[w][tid];
        P[(size_t)vtile * NROW + row0 + tid] = tot;
    }
}

__global__ __launch_bounds__(512, 4) void write_logits(
    const float* __restrict__ H, const float* __restrict__ Wo,
    const float* __restrict__ P, float* __restrict__ out)
{
    __shared__ __align__(16) float sLogS[RV];

    const int tid = threadIdx.x;
    const int vtile = blockIdx.x & 15;
    const int row0 = (blockIdx.x >> 4) * RV;

    if (tid < RV) {  // fused logS: sum 16 partials for row (row0+tid)
        float tot = 0.f;
        #pragma unroll
        for (int p = 0; p < 16; ++p) tot += P[(size_t)p * NROW + row0 + tid];
        sLogS[tid] = __logf(tot);
    }
    __syncthreads();

    const int v = vtile * VSK + 4 * tid;
    if (v >= VOCAB) return;  // tail; no barriers below

    f32x2 wlo[HID], whi[HID];
    #pragma unroll
    for (int k = 0; k < HID; ++k) {
        f32x4 w4 = *(const f32x4*)(Wo + (size_t)k * VOCAB + v);
        wlo[k] = w4.xy; whi[k] = w4.zw;
    }
    const double* H2 = (const double*)(H + row0 * HID);
    const f32x4* sLS4 = (const f32x4*)sLogS;

    float* orow = out + (size_t)row0 * VOCAB + v;
    for (int r4 = 0; r4 < RV; r4 += 4) {
        f32x4 ls4 = sLS4[r4 >> 2];
        #pragma unroll
        for (int rr = 0; rr < 4; ++rr) {
            const int r = r4 + rr;
            f32x2 a01 = {0.f, 0.f}, a23 = {0.f, 0.f};
            f32x2 b01 = {0.f, 0.f}, b23 = {0.f, 0.f};
            #pragma unroll
            for (int q = 0; q < 8; ++q) {
                double h2 = H2[r * 8 + q];  // uniform s_load
                pk_fma_lo(a01, h2, wlo[2 * q]);
                pk_fma_lo(a23, h2, whi[2 * q]);
                pk_fma_hi(b01, h2, wlo[2 * q + 1]);
                pk_fma_hi(b23, h2, whi[2 * q + 1]);
            }
            const float ls = (rr == 0) ? ls4.x : (rr == 1) ? ls4.y
                           : (rr == 2) ? ls4.z : ls4.w;
            f32x4 o;
            o.x = (a01.x + b01.x) - ls; o.y = (a01.y + b01.y) - ls;
            o.z = (a23.x + b23.x) - ls; o.w = (a23.y + b23.y) - ls;
            __builtin_nontemporal_store(o, (f32x4*)orow);
            orow += VOCAB;
        }
    }
}

extern "C" void kernel_launch(void* const* d_in, const int* in_sizes, int n_in,
                              void* d_out, int out_size, void* d_ws, size_t ws_size,
                              hipStream_t stream) {
    const int*   idx    = (const int*)d_in[0];    // [SEQ, BATCH] int32
    const float* lookup = (const float*)d_in[1];  // [VOCAB, EMB]
    const float* Wx     = (const float*)d_in[2];  // [EMB, HID]
    const float* Wh     = (const float*)d_in[3];  // [HID, HID]
    const float* Wo     = (const float*)d_in[4];  // [HID, VOCAB]
    float* out = (float*)d_out;                   // [SEQ, BATCH, VOCAB]

    // ws layout: H (256 KB) | P partials 16x4096 (256 KB)
    float* Hbuf = (float*)d_ws;
    float* P    = Hbuf + NROW * HID;

    rnn_recur<<<1, 512, 0, stream>>>(idx, lookup, Wx, Wh, Hbuf);
    sum_exp_partial<<<16 * (NROW / RV), 512, 0, stream>>>(Hbuf, Wo, P);
    write_logits<<<16 * (NROW / RV), 512, 0, stream>>>(Hbuf, Wo, P, out);
}

// Round 14
// 207.739 us; speedup vs baseline: 3.0338x; 1.2399x over previous
//
#include <hip/hip_runtime.h>

#define VOCAB 32000
#define EMB 32
#define HID 16
#define SEQ 128
#define BATCH 32
#define NROW (SEQ * BATCH)  // 4096 rows

typedef float f32x2 __attribute__((ext_vector_type(2)));
typedef float f32x4 __attribute__((ext_vector_type(4)));

// ---------------------------------------------------------------------------
// K0: A[t][b][j] = sum_e lookup[idx[t,b]][e] * Wx[e][j]  (no serial dep ->
// fully parallel; removes 2/3 of the serial step's FMA chain). 128 blocks.
// ---------------------------------------------------------------------------
__global__ __launch_bounds__(512) void embed_xw(
    const int* __restrict__ idx, const float* __restrict__ lookup,
    const float* __restrict__ Wx, float* __restrict__ A)
{
    __shared__ float sWx[EMB][HID];
    const int tid = threadIdx.x;
    ((float*)sWx)[tid] = Wx[tid];  // 512 == EMB*HID
    __syncthreads();

    const int g = blockIdx.x * 512 + tid;  // 0..65535
    const int row = g >> 4, j = g & 15;
    const float* xr = lookup + (size_t)idx[row] * EMB;  // 16 threads share row
    float a0 = 0.f, a1 = 0.f;
    #pragma unroll
    for (int e = 0; e < EMB; e += 2) {
        a0 += xr[e] * sWx[e][j];
        a1 += xr[e + 1] * sWx[e + 1][j];
    }
    A[g] = a0 + a1;
}

// ---------------------------------------------------------------------------
// K1: serial recurrence, A precomputed. One block, 512 thr = 32 b x 16 j.
// Wh column j in registers; per step: 4 ds_read_b128 (sH row) + 16 FMA +
// tanh-trick. Per-step deps stay in a 16-lane group -> no per-step barrier
// (same-wave DS ordering, validated rounds 1-13).
// ---------------------------------------------------------------------------
__global__ __launch_bounds__(512) void rnn_recur(
    const float* __restrict__ A, const float* __restrict__ Wh,
    float* __restrict__ Hout)
{
    __shared__ __align__(16) float sH[BATCH][HID];

    const int tid = threadIdx.x;
    const int b = tid >> 4, j = tid & 15;

    float wh[HID];
    #pragma unroll
    for (int k = 0; k < HID; ++k) wh[k] = Wh[k * HID + j];  // column j

    sH[b][j] = 1.0f;  // torch inits H to ones
    __syncthreads();

    float a0r = A[0 * 512 + tid];
    float a1r = A[1 * 512 + tid];
    float a2r = A[2 * 512 + tid];
    float a3r = A[3 * 512 + tid];

#define RNN_STEP(AR, T)                                                     \
    {                                                                       \
        float acc = AR;                                                     \
        if ((T) + 4 < SEQ) AR = A[((T) + 4) * 512 + tid];                   \
        const f32x4* sH4 = (const f32x4*)&sH[b][0];                         \
        f32x4 h0 = sH4[0], h1 = sH4[1], h2v = sH4[2], h3v = sH4[3];         \
        acc += h0.x * wh[0] + h0.y * wh[1] + h0.z * wh[2] + h0.w * wh[3];   \
        acc += h1.x * wh[4] + h1.y * wh[5] + h1.z * wh[6] + h1.w * wh[7];   \
        acc += h2v.x * wh[8] + h2v.y * wh[9] + h2v.z * wh[10]               \
             + h2v.w * wh[11];                                              \
        acc += h3v.x * wh[12] + h3v.y * wh[13] + h3v.z * wh[14]             \
             + h3v.w * wh[15];                                              \
        float e2 = __expf(2.f * acc);   /* tanh = 1 - 2/(e^{2a}+1) */       \
        float h = 1.f - 2.f / (e2 + 1.f);                                   \
        sH[b][j] = h;                                                       \
        Hout[(T) * 512 + tid] = h;                                          \
    }

    for (int t = 0; t < SEQ; t += 4) {
        RNN_STEP(a0r, t + 0)
        RNN_STEP(a1r, t + 1)
        RNN_STEP(a2r, t + 2)
        RNN_STEP(a3r, t + 3)
    }
#undef RNN_STEP
}

// ---------------------------------------------------------------------------
// K2: sum-of-exp, LANE = ROW layout (round-14 inversion). Wave = 64 rows x
// 500-col slice. H: 16 per-lane VGPRs (loaded once, provably fits). Wo:
// wave-uniform addresses -> s_load (SMEM pipe). Exp-sum accumulates IN-LANE:
// no DPP/shfl reduce, no LDS staging, no tail (64*500 = 32000 exact).
// v_pk_fma_f32: h-pair (VGPR) x Wo-pair (SGPR, 1 scalar read: legal).
// Block = 8 waves = one 4000-col chunk x 64 rows; cross-wave combine in LDS.
// ---------------------------------------------------------------------------
#define CSL 500  // cols per wave slice

__global__ __launch_bounds__(512, 4) void sum_exp_partial(
    const float* __restrict__ H, const float* __restrict__ Wo,
    float* __restrict__ P)
{
    __shared__ float part[8][64];

    const int tid = threadIdx.x;
    const int lane = tid & 63;
    const int wave = tid >> 6;                    // 0..7
    const int rgrp = blockIdx.x >> 3;             // 0..63
    const int cchunk = blockIdx.x & 7;            // 0..7
    const int row0 = rgrp * 64;
    // wave-uniform col base (readfirstlane: make uniformity provable)
    const int c0 = __builtin_amdgcn_readfirstlane(cchunk * 4000 + wave * CSL);

    // per-lane H row -> broadcast pairs for pk_fma
    f32x2 hp[HID];
    {
        const f32x4* h4 = (const f32x4*)(H + (size_t)(row0 + lane) * HID);
        #pragma unroll
        for (int q = 0; q < 4; ++q) {
            f32x4 hv = h4[q];
            hp[4 * q + 0] = f32x2{hv.x, hv.x};
            hp[4 * q + 1] = f32x2{hv.y, hv.y};
            hp[4 * q + 2] = f32x2{hv.z, hv.z};
            hp[4 * q + 3] = f32x2{hv.w, hv.w};
        }
    }

    const float* wbase = Wo + c0;
    float acc0 = 0.f, acc1 = 0.f, acc2 = 0.f, acc3 = 0.f;
    for (int v = 0; v < CSL; v += 4) {
        f32x2 a01 = {0.f, 0.f}, a23 = {0.f, 0.f};
        #pragma unroll
        for (int k = 0; k < HID; ++k) {
            f32x4 w4 = *(const f32x4*)(wbase + (size_t)k * VOCAB + v);
            asm("v_pk_fma_f32 %0, %1, %2, %0"
                : "+v"(a01) : "v"(hp[k]), "s"(w4.xy));
            asm("v_pk_fma_f32 %0, %1, %2, %0"
                : "+v"(a23) : "v"(hp[k]), "s"(w4.zw));
        }
        acc0 += __expf(a01.x); acc1 += __expf(a01.y);
        acc2 += __expf(a23.x); acc3 += __expf(a23.y);
    }

    part[wave][lane] = (acc0 + acc1) + (acc2 + acc3);
    __syncthreads();
    if (wave == 0) {
        float tot = 0.f;
        #pragma unroll
        for (int w = 0; w < 8; ++w) tot += part[w][lane];
        P[(size_t)cchunk * NROW + row0 + lane] = tot;  // written exactly once
    }
}

// ---------------------------------------------------------------------------
// K3: output pass — EXACT R11-measured structure (107us = NT-store BW floor:
// WRITE 1.0x, FETCH ~3MB, ~4.9 TB/s): LDS sH + plain FMA + NT float4 stores.
// logS fused from 8 partials. NT mandatory (R6: write-back RFO-thrash).
// ---------------------------------------------------------------------------
#define RV 64     // rows per block
#define VSK 2048  // vocab cols per block slice

__global__ __launch_bounds__(512, 4) void write_logits(
    const float* __restrict__ H, const float* __restrict__ Wo,
    const float* __restrict__ P, float* __restrict__ out)
{
    __shared__ __align__(16) float sH[RV * HID];  // 4 KB
    __shared__ __align__(16) float sLogS[RV];

    const int tid = threadIdx.x;
    const int vtile = blockIdx.x & 15;
    const int row0 = (blockIdx.x >> 4) * RV;

    if (tid < RV * HID / 4)
        *(float4*)(sH + 4 * tid) = *(const float4*)(H + row0 * HID + 4 * tid);
    if (tid < RV) {  // fused logS: 8 partials per row
        float tot = 0.f;
        #pragma unroll
        for (int p = 0; p < 8; ++p) tot += P[(size_t)p * NROW + row0 + tid];
        sLogS[tid] = __logf(tot);
    }
    __syncthreads();

    const int v = vtile * VSK + 4 * tid;
    if (v >= VOCAB) return;  // tile-15 tail; no barriers below

    f32x2 wlo[HID], whi[HID];
    #pragma unroll
    for (int k = 0; k < HID; ++k) {
        f32x4 w4 = *(const f32x4*)(Wo + (size_t)k * VOCAB + v);
        wlo[k] = w4.xy; whi[k] = w4.zw;
    }
    const f32x4* sH4 = (const f32x4*)sH;
    const f32x4* sLS4 = (const f32x4*)sLogS;

    float* orow = out + (size_t)row0 * VOCAB + v;
    for (int r4 = 0; r4 < RV; r4 += 4) {
        f32x4 ls4 = sLS4[r4 >> 2];
        #pragma unroll
        for (int rr = 0; rr < 4; ++rr) {
            const int r = r4 + rr;
            f32x2 l01 = {0.f, 0.f}, l23 = {0.f, 0.f};
            #pragma unroll
            for (int q = 0; q < 4; ++q) {
                f32x4 hv = sH4[r * 4 + q];  // uniform addr b128 broadcast
                l01 += hv.x * wlo[4*q+0]; l23 += hv.x * whi[4*q+0];
                l01 += hv.y * wlo[4*q+1]; l23 += hv.y * whi[4*q+1];
                l01 += hv.z * wlo[4*q+2]; l23 += hv.z * whi[4*q+2];
                l01 += hv.w * wlo[4*q+3]; l23 += hv.w * whi[4*q+3];
            }
            const float ls = (rr == 0) ? ls4.x : (rr == 1) ? ls4.y
                           : (rr == 2) ? ls4.z : ls4.w;
            f32x4 o;
            o.xy = l01 - ls;
            o.zw = l23 - ls;
            __builtin_nontemporal_store(o, (f32x4*)orow);
            orow += VOCAB;
        }
    }
}

extern "C" void kernel_launch(void* const* d_in, const int* in_sizes, int n_in,
                              void* d_out, int out_size, void* d_ws, size_t ws_size,
                              hipStream_t stream) {
    const int*   idx    = (const int*)d_in[0];    // [SEQ, BATCH] int32
    const float* lookup = (const float*)d_in[1];  // [VOCAB, EMB]
    const float* Wx     = (const float*)d_in[2];  // [EMB, HID]
    const float* Wh     = (const float*)d_in[3];  // [HID, HID]
    const float* Wo     = (const float*)d_in[4];  // [HID, VOCAB]
    float* out = (float*)d_out;                   // [SEQ, BATCH, VOCAB]

    // ws layout: H (256 KB) | A = X@Wx (256 KB) | P partials 8x4096 (128 KB)
    float* Hbuf = (float*)d_ws;
    float* A    = Hbuf + NROW * HID;
    float* P    = A + NROW * HID;

    embed_xw<<<128, 512, 0, stream>>>(idx, lookup, Wx, A);
    rnn_recur<<<1, 512, 0, stream>>>(A, Wh, Hbuf);
    sum_exp_partial<<<512, 512, 0, stream>>>(Hbuf, Wo, P);
    write_logits<<<16 * (NROW / RV), 512, 0, stream>>>(Hbuf, Wo, P, out);
}